// Round 5
// baseline (541.970 us; speedup 1.0000x reference)
//
#include <hip/hip_runtime.h>
#include <cstdint>

// B=4, S=2048, H=512, NH=8, HD=64 — 5 launches:
//   cvt_w | mask_bits | qkv_gemm (fused fp32-staged, z=q/k/v) | attn (pipelined) | out_gemm
// ws: Oh 0-8Mi | Qh 8-16 | Kh 16-24 | Vt 24-32 | MB 32-34 | Wb 34-36 MiB

typedef __bf16 bf16x8 __attribute__((ext_vector_type(8)));
typedef float  f32x4  __attribute__((ext_vector_type(4)));
typedef float  f32x16 __attribute__((ext_vector_type(16)));

#define MFMA16(a, b, c) __builtin_amdgcn_mfma_f32_16x16x32_bf16(a, b, c, 0, 0, 0)
#define MFMA32(a, b, c) __builtin_amdgcn_mfma_f32_32x32x16_bf16(a, b, c, 0, 0, 0)

__device__ __forceinline__ ushort f2bf(float f) {
  union { __bf16 h; ushort u; } v; v.h = (__bf16)f; return v.u;
}

typedef const __attribute__((address_space(1))) unsigned int* gas_u32;
typedef __attribute__((address_space(3))) unsigned int* las_u32;
__device__ __forceinline__ void gll16(const void* g, void* l) {
  __builtin_amdgcn_global_load_lds((gas_u32)g, (las_u32)l, 16, 0, 0);
}

// ---------------------------------------------------------------- weights cvt
__global__ __launch_bounds__(256) void cvt_w(
    const float* __restrict__ w0, const float* __restrict__ w1,
    const float* __restrict__ w2, const float* __restrict__ w3,
    ushort* __restrict__ dst) {
  const float* src = (blockIdx.y == 0) ? w0 : (blockIdx.y == 1) ? w1
                   : (blockIdx.y == 2) ? w2 : w3;
  ushort* d = dst + (size_t)blockIdx.y * 262144;
  int i = blockIdx.x * 256 + threadIdx.x;
  for (int j = i; j < 65536; j += 16384) {
    float4 v = ((const float4*)src)[j];
    ushort4 o = { f2bf(v.x), f2bf(v.y), f2bf(v.z), f2bf(v.w) };
    ((ushort4*)d)[j] = o;
  }
}

// ---------------------------------------------------------------- mask bits
__global__ __launch_bounds__(256) void mask_bits_kernel(
    const int* __restrict__ mask, unsigned long long* __restrict__ MB) {
  const int lane = threadIdx.x & 63;
  const int wv = (int)((blockIdx.x * 256 + threadIdx.x) >> 6);
  const size_t base = (size_t)wv * 64;
  for (int j = 0; j < 64; j += 4) {
    int v0 = mask[(base + j + 0) * 64 + lane];
    int v1 = mask[(base + j + 1) * 64 + lane];
    int v2 = mask[(base + j + 2) * 64 + lane];
    int v3 = mask[(base + j + 3) * 64 + lane];
    unsigned long long b0 = __ballot(v0 != 0), b1 = __ballot(v1 != 0);
    unsigned long long b2 = __ballot(v2 != 0), b3 = __ballot(v3 != 0);
    if (lane == 0) {
      MB[base + j] = b0; MB[base + j + 1] = b1;
      MB[base + j + 2] = b2; MB[base + j + 3] = b3;
    }
  }
}

// ---------------------------------------------------------------- QKV GEMM
// Y[8192][512] = X f32 [m][k] * W bf16 [n][k]; tile 64x128, BK=64.
// z=0: Q, scale=0.125*log2(e); z=1: K; z=2: V transposed [b][h][hd][s].
__global__ __launch_bounds__(256) void qkv_gemm(
    const float* __restrict__ q, const float* __restrict__ k,
    const float* __restrict__ v, const ushort* __restrict__ Wb,
    const float* __restrict__ bq, const float* __restrict__ bk,
    const float* __restrict__ bv, ushort* __restrict__ Qh,
    ushort* __restrict__ Kh, ushort* __restrict__ Vt) {
  __shared__ float  Asf[64 * 64];
  __shared__ ushort Ws[128 * 64];
  const int z = blockIdx.z;
  const float* X = (z == 0) ? q : (z == 1) ? k : v;
  const ushort* W = Wb + (size_t)z * 262144;
  const float* bias = (z == 0) ? bq : (z == 1) ? bk : bv;
  const float scale = (z == 0) ? 0.18033688011112042f : 1.0f;
  ushort* Y = (z == 0) ? Qh : (z == 1) ? Kh : Vt;

  const int tid = threadIdx.x, wv = tid >> 6, l = tid & 63;
  const int quad = l >> 4, ln = l & 15;
  const int m0 = blockIdx.x * 64, n0 = blockIdx.y * 128;
  const int wm = (wv & 1) * 32, wn = (wv >> 1) * 64;
  const int srA = l >> 4, sA = l & 15, cA = sA >> 1, hA = sA & 1;
  const int srW = l >> 3, scW = l & 7;
  f32x4 acc[2][4] = {};

  for (int kk = 0; kk < 512; kk += 64) {
#pragma unroll
    for (int i = 0; i < 4; ++i) {
      int rowa = wv * 16 + i * 4 + srA;
      gll16(X + (size_t)(m0 + rowa) * 512 + kk + ((cA ^ (rowa & 7)) * 8 + hA * 4),
            Asf + (wv * 16 + i * 4) * 64);
      int roww = wv * 32 + i * 8 + srW;
      gll16(W + (size_t)(n0 + roww) * 512 + kk + ((scW ^ (roww & 7)) * 8),
            Ws + (wv * 32 + i * 8) * 64);
    }
    __syncthreads();
#pragma unroll
    for (int ks = 0; ks < 2; ++ks) {
      bf16x8 a[2], bw[4];
#pragma unroll
      for (int mt = 0; mt < 2; ++mt) {
        int row = wm + mt * 16 + ln;
        int p = (ks * 4 + quad) ^ (row & 7);
        const float* ap = &Asf[row * 64 + p * 8];
        f32x4 x0 = *(const f32x4*)ap;
        f32x4 x1 = *(const f32x4*)(ap + 4);
        bf16x8 t;
#pragma unroll
        for (int j = 0; j < 4; ++j) { t[j] = (__bf16)x0[j]; t[4 + j] = (__bf16)x1[j]; }
        a[mt] = t;
      }
#pragma unroll
      for (int nt = 0; nt < 4; ++nt) {
        int row = wn + nt * 16 + ln;
        bw[nt] = *(const bf16x8*)&Ws[row * 64 + (((ks * 4 + quad) ^ (row & 7)) * 8)];
      }
#pragma unroll
      for (int mt = 0; mt < 2; ++mt)
#pragma unroll
        for (int nt = 0; nt < 4; ++nt)
          acc[mt][nt] = MFMA16(a[mt], bw[nt], acc[mt][nt]);
    }
    __syncthreads();
  }
  float bval[4];
#pragma unroll
  for (int nt = 0; nt < 4; ++nt) bval[nt] = bias[n0 + wn + nt * 16 + ln];

  if (z == 2) {
#pragma unroll
    for (int nt = 0; nt < 4; ++nt) {
      int row = wn + nt * 16 + ln;
#pragma unroll
      for (int mt = 0; mt < 2; ++mt) {
        int mbase = wm + mt * 16 + quad * 4;
        ushort4 pk;
        pk.x = f2bf(acc[mt][nt][0] + bval[nt]);
        pk.y = f2bf(acc[mt][nt][1] + bval[nt]);
        pk.z = f2bf(acc[mt][nt][2] + bval[nt]);
        pk.w = f2bf(acc[mt][nt][3] + bval[nt]);
        int col = ((mbase >> 3) ^ (row & 7)) * 8 + ((mbase >> 2) & 1) * 4;
        *(ushort4*)&Ws[row * 64 + col] = pk;
      }
    }
    __syncthreads();
#pragma unroll
    for (int i = 0; i < 4; ++i) {
      int c = tid + i * 256;
      int row = c >> 3, cs = c & 7;
      int cl = cs ^ (row & 7);
      uint4 d = *(const uint4*)&Ws[row * 64 + cs * 8];
      int n = n0 + row, m = m0 + cl * 8;
      int bb = m >> 11, s = m & 2047, h = n >> 6, hd = n & 63;
      *(uint4*)(Y + ((size_t)((bb * 8 + h) * 64 + hd)) * 2048 + s) = d;
    }
  } else {
#pragma unroll
    for (int mt = 0; mt < 2; ++mt)
#pragma unroll
      for (int nt = 0; nt < 4; ++nt) {
        int n = n0 + wn + nt * 16 + ln;
#pragma unroll
        for (int r = 0; r < 4; ++r) {
          int m = m0 + wm + mt * 16 + quad * 4 + r;
          float val = (acc[mt][nt][r] + bval[nt]) * scale;
          int bb = m >> 11, s = m & 2047, h = n >> 6, hd = n & 63;
          Y[(((size_t)(bb * 8 + h) * 2048) + s) * 64 + hd] = f2bf(val);
        }
      }
  }
}

// ---------------------------------------------------------------- attention
// 32x32x16 MFMA, S^T = K.Q^T, P^T->B-frag via shfl_xor(32). Software-pipelined
// K/V staging through VGPRs (global_load -> regs overlaps compute of prev tile).
__global__ __launch_bounds__(256, 4) void attn(
    const ushort* __restrict__ Qh, const ushort* __restrict__ Kh,
    const ushort* __restrict__ Vt, const unsigned long long* __restrict__ MB,
    ushort* __restrict__ O) {
  __shared__ ushort SMEM[16384];          // Ks 16KB | Vs 16KB (reused at end)
  ushort* Ks = SMEM;                      // [kv 128][d 64], chunk-swizzled
  ushort* Vs = SMEM + 8192;               // [hd 64][kv 128], chunk-swizzled
  const int tid = threadIdx.x, wv = tid >> 6, lane = tid & 63;
  const int hs = lane >> 5, lq = lane & 31;
  const int qh = wv >> 1, kvh = wv & 1;
  const int bh = blockIdx.x, qb = blockIdx.y;
  const size_t hoff = (size_t)bh * 2048 * 64;
  const int q0 = qb * 64;
  const int qg = q0 + qh * 32 + lq;
  const int srK = lane >> 3, scK = lane & 7;
  const int srV = lane >> 4, scV = lane & 15;
  const ushort* Kbase = Kh + hoff;
  const ushort* Vbase = Vt + hoff;

  bf16x8 qf[4];                            // B-frag: k = 16*ki + 8*hs + j
#pragma unroll
  for (int ki = 0; ki < 4; ++ki)
    qf[ki] = *(const bf16x8*)(Qh + hoff + (size_t)qg * 64 + ki * 16 + hs * 8);

  // per-wave staging constants
  int lK[4], lV[4];
  size_t gK[4], gV[4];
#pragma unroll
  for (int i = 0; i < 4; ++i) {
    int rowK = wv * 32 + i * 8 + srK;
    gK[i] = (size_t)rowK * 64 + ((scK ^ (rowK & 7)) * 8);
    lK[i] = rowK * 64 + scK * 8;
    int rowV = wv * 16 + i * 4 + srV;
    gV[i] = (size_t)rowV * 2048 + ((scV ^ (rowV & 7)) * 8);
    lV[i] = rowV * 128 + scV * 8;
  }

  f32x16 po0 = {}, po1 = {};               // O^T accum, col=q
  float l_own = 0.f;
  const unsigned long long* mrow = MB + ((size_t)(bh >> 3) * 2048 + qg) * 32;

  uint4 kr[2][4], vr[2][4];
  unsigned long long mb[2];
#pragma unroll
  for (int i = 0; i < 4; ++i) {            // prologue: prefetch tile 0
    kr[0][i] = *(const uint4*)(Kbase + gK[i]);
    vr[0][i] = *(const uint4*)(Vbase + gV[i]);
  }
  mb[0] = mrow[kvh];

#pragma unroll 2
  for (int it = 0; it < 16; ++it) {
    const int p = it & 1;
#pragma unroll
    for (int i = 0; i < 4; ++i) {          // write tile it to LDS
      *(uint4*)&Ks[lK[i]] = kr[p][i];
      *(uint4*)&Vs[lV[i]] = vr[p][i];
    }
    if (it < 15) {                         // prefetch tile it+1 (latency hidden)
      const size_t kvo = (size_t)(it + 1) * 128;
#pragma unroll
      for (int i = 0; i < 4; ++i) {
        kr[p ^ 1][i] = *(const uint4*)(Kbase + kvo * 64 + gK[i]);
        vr[p ^ 1][i] = *(const uint4*)(Vbase + kvo + gV[i]);
      }
      mb[p ^ 1] = mrow[(it + 1) * 2 + kvh];
    }
    __syncthreads();

    const unsigned long long mbw = mb[p];
#pragma unroll
    for (int ch = 0; ch < 2; ++ch) {       // two 32-kv chunks for this wave
      const int kvb = kvh * 64 + ch * 32;
      f32x16 sc_ = {};
#pragma unroll
      for (int ki = 0; ki < 4; ++ki) {
        int row = kvb + lq;
        bf16x8 ak = *(const bf16x8*)&Ks[row * 64 + (((2 * ki + hs) ^ (row & 7)) * 8)];
        sc_ = MFMA32(ak, qf[ki], sc_);
      }
      uint pk[8];
      float psum = 0.f;
#pragma unroll
      for (int c = 0; c < 4; ++c) {
        unsigned nib = (unsigned)(mbw >> (ch * 32 + c * 8 + hs * 4)) & 0xFu;
        float p0 = (nib & 1u) ? exp2f(sc_[4 * c + 0]) : 0.f;
        float p1 = (nib & 2u) ? exp2f(sc_[4 * c + 1]) : 0.f;
        float p2 = (nib & 4u) ? exp2f(sc_[4 * c + 2]) : 0.f;
        float p3 = (nib & 8u) ? exp2f(sc_[4 * c + 3]) : 0.f;
        psum += (p0 + p1) + (p2 + p3);
        pk[2 * c + 0] = (uint)f2bf(p0) | ((uint)f2bf(p1) << 16);
        pk[2 * c + 1] = (uint)f2bf(p2) | ((uint)f2bf(p3) << 16);
      }
      l_own += psum;
      uint bx[4];
#pragma unroll
      for (int t2 = 0; t2 < 2; ++t2)
#pragma unroll
        for (int b2 = 0; b2 < 2; ++b2) {
          uint snd = hs ? pk[4 * t2 + b2] : pk[4 * t2 + 2 + b2];
          bx[t2 * 2 + b2] = (uint)__shfl_xor((int)snd, 32);
        }
#pragma unroll
      for (int t2 = 0; t2 < 2; ++t2) {
        union { uint u[4]; bf16x8 v; } bp;
        bp.u[0] = hs ? bx[2 * t2 + 0] : pk[4 * t2 + 0];
        bp.u[1] = hs ? bx[2 * t2 + 1] : pk[4 * t2 + 1];
        bp.u[2] = hs ? pk[4 * t2 + 2] : bx[2 * t2 + 0];
        bp.u[3] = hs ? pk[4 * t2 + 3] : bx[2 * t2 + 1];
#pragma unroll
        for (int m2 = 0; m2 < 2; ++m2) {
          int hd = m2 * 32 + lq;
          int gch = (kvb >> 3) + 2 * t2 + hs;
          bf16x8 av = *(const bf16x8*)&Vs[hd * 128 + ((gch ^ (hd & 7)) * 8)];
          if (m2 == 0) po0 = MFMA32(av, bp.v, po0);
          else         po1 = MFMA32(av, bp.v, po1);
        }
      }
    }
    __syncthreads();
  }

  // ---- merge kv-halves + epilogue
  l_own += __shfl_xor(l_own, 32);
  float* psh = (float*)Ks;                 // [64 q][64 hd] f32
  float* lsh = (float*)Vs;                 // [qh][64]
  ushort* Osh = Vs + 256;                  // [64 q][72]
  if (kvh == 1) {
#pragma unroll
    for (int i = 0; i < 16; ++i) psh[(qh * 32 + i) * 64 + lane] = po0[i];
#pragma unroll
    for (int i = 0; i < 16; ++i) psh[(qh * 32 + 16 + i) * 64 + lane] = po1[i];
    lsh[qh * 64 + lane] = l_own;
  }
  __syncthreads();
  if (kvh == 0) {
    float linv = 1.0f / (l_own + lsh[qh * 64 + lane]);
    int row = qh * 32 + lq;
#pragma unroll
    for (int m2 = 0; m2 < 2; ++m2) {
#pragma unroll
      for (int c = 0; c < 4; ++c)
#pragma unroll
        for (int b2 = 0; b2 < 2; ++b2) {
          int r = 4 * c + 2 * b2;
          float v0, v1;
          if (m2 == 0) {
            v0 = (po0[r] + psh[(qh * 32 + r) * 64 + lane]) * linv;
            v1 = (po0[r + 1] + psh[(qh * 32 + r + 1) * 64 + lane]) * linv;
          } else {
            v0 = (po1[r] + psh[(qh * 32 + 16 + r) * 64 + lane]) * linv;
            v1 = (po1[r + 1] + psh[(qh * 32 + 16 + r + 1) * 64 + lane]) * linv;
          }
          int hd = m2 * 32 + 8 * c + 4 * hs + 2 * b2;
          *(uint*)&Osh[row * 72 + hd] = (uint)f2bf(v0) | ((uint)f2bf(v1) << 16);
        }
    }
  }
  __syncthreads();
  for (int i = tid; i < 512; i += 256) {
    int row = i >> 3, cc = i & 7;
    uint4 d = *(const uint4*)&Osh[row * 72 + cc * 8];
    *(uint4*)(O + ((size_t)((bh >> 3) * 2048 + q0 + row)) * 512 +
              (bh & 7) * 64 + cc * 8) = d;
  }
}

// ---------------------------------------------------------------- out proj
__global__ __launch_bounds__(256) void out_gemm(
    const ushort* __restrict__ X, const ushort* __restrict__ W,
    const float* __restrict__ bias, float* __restrict__ Y) {
  __shared__ ushort As[64 * 64];
  __shared__ ushort Ws[128 * 64];
  const int tid = threadIdx.x, wv = tid >> 6, l = tid & 63;
  const int quad = l >> 4, ln = l & 15;
  const int m0 = blockIdx.x * 64, n0 = blockIdx.y * 128;
  const int wm = (wv & 1) * 32, wn = (wv >> 1) * 64;
  const int sr = l >> 3, sc = l & 7;
  f32x4 acc[2][4] = {};
  for (int kk = 0; kk < 512; kk += 64) {
#pragma unroll
    for (int i = 0; i < 2; ++i) {
      int row = wv * 16 + i * 8 + sr;
      gll16(X + (size_t)(m0 + row) * 512 + kk + ((sc ^ (row & 7)) * 8),
            As + (wv * 16 + i * 8) * 64);
    }
#pragma unroll
    for (int i = 0; i < 4; ++i) {
      int row = wv * 32 + i * 8 + sr;
      gll16(W + (size_t)(n0 + row) * 512 + kk + ((sc ^ (row & 7)) * 8),
            Ws + (wv * 32 + i * 8) * 64);
    }
    __syncthreads();
#pragma unroll
    for (int ks = 0; ks < 2; ++ks) {
      bf16x8 a[2], bw[4];
#pragma unroll
      for (int mt = 0; mt < 2; ++mt) {
        int row = wm + mt * 16 + ln;
        a[mt] = *(const bf16x8*)&As[row * 64 + (((ks * 4 + quad) ^ (row & 7)) * 8)];
      }
#pragma unroll
      for (int nt = 0; nt < 4; ++nt) {
        int row = wn + nt * 16 + ln;
        bw[nt] = *(const bf16x8*)&Ws[row * 64 + (((ks * 4 + quad) ^ (row & 7)) * 8)];
      }
#pragma unroll
      for (int mt = 0; mt < 2; ++mt)
#pragma unroll
        for (int nt = 0; nt < 4; ++nt)
          acc[mt][nt] = MFMA16(a[mt], bw[nt], acc[mt][nt]);
    }
    __syncthreads();
  }
#pragma unroll
  for (int mt = 0; mt < 2; ++mt)
#pragma unroll
    for (int nt = 0; nt < 4; ++nt) {
      int n = n0 + wn + nt * 16 + ln;
      float bval = bias[n];
#pragma unroll
      for (int r = 0; r < 4; ++r) {
        int m = m0 + wm + mt * 16 + quad * 4 + r;
        Y[(size_t)m * 512 + n] = acc[mt][nt][r] + bval;
      }
    }
}

// ---------------------------------------------------------------- launch
extern "C" void kernel_launch(void* const* d_in, const int* in_sizes, int n_in,
                              void* d_out, int out_size, void* d_ws, size_t ws_size,
                              hipStream_t stream) {
  const float* q    = (const float*)d_in[0];
  const float* k    = (const float*)d_in[1];
  const float* v    = (const float*)d_in[2];
  const int*   mask = (const int*)d_in[3];
  const float* Wq   = (const float*)d_in[4];
  const float* bq   = (const float*)d_in[5];
  const float* Wk   = (const float*)d_in[6];
  const float* bk   = (const float*)d_in[7];
  const float* Wv   = (const float*)d_in[8];
  const float* bv   = (const float*)d_in[9];
  const float* Wo   = (const float*)d_in[10];
  const float* bo   = (const float*)d_in[11];
  float* out = (float*)d_out;

  uint8_t* ws = (uint8_t*)d_ws;
  const size_t MiB = 1u << 20;
  ushort* Oh = (ushort*)(ws + 0 * MiB);
  ushort* Qh = (ushort*)(ws + 8 * MiB);
  ushort* Kh = (ushort*)(ws + 16 * MiB);
  ushort* Vt = (ushort*)(ws + 24 * MiB);
  unsigned long long* MB = (unsigned long long*)(ws + 32 * MiB);
  ushort* Wb = (ushort*)(ws + 34 * MiB);

  cvt_w<<<dim3(64, 4), 256, 0, stream>>>(Wq, Wk, Wv, Wo, Wb);
  mask_bits_kernel<<<1024, 256, 0, stream>>>(mask, MB);
  qkv_gemm<<<dim3(128, 4, 3), 256, 0, stream>>>(q, k, v, Wb, bq, bk, bv, Qh, Kh, Vt);
  attn<<<dim3(32, 32), 256, 0, stream>>>(Qh, Kh, Vt, MB, Oh);
  out_gemm<<<dim3(128, 4), 256, 0, stream>>>(Oh, Wb + 3 * 262144, bo, out);
}

// Round 6
// 268.481 us; speedup vs baseline: 2.0187x; 2.0187x over previous
//
#include <hip/hip_runtime.h>
#include <cstdint>

// B=4, S=2048, H=512, NH=8, HD=64 — 5 launches:
//   cvt_w | mask_bits | qkv_gemm (128x128 tile, fp32-staged, z=q/k/v) | attn (R4) | out_gemm
// ws: Oh 0-8Mi | Qh 8-16 | Kh 16-24 | Vt 24-32 | MB 32-34 | Wb 34-36 MiB

typedef __bf16 bf16x8 __attribute__((ext_vector_type(8)));
typedef float  f32x4  __attribute__((ext_vector_type(4)));
typedef float  f32x16 __attribute__((ext_vector_type(16)));

#define MFMA16(a, b, c) __builtin_amdgcn_mfma_f32_16x16x32_bf16(a, b, c, 0, 0, 0)
#define MFMA32(a, b, c) __builtin_amdgcn_mfma_f32_32x32x16_bf16(a, b, c, 0, 0, 0)

__device__ __forceinline__ ushort f2bf(float f) {
  union { __bf16 h; ushort u; } v; v.h = (__bf16)f; return v.u;
}

typedef const __attribute__((address_space(1))) unsigned int* gas_u32;
typedef __attribute__((address_space(3))) unsigned int* las_u32;
__device__ __forceinline__ void gll16(const void* g, void* l) {
  __builtin_amdgcn_global_load_lds((gas_u32)g, (las_u32)l, 16, 0, 0);
}

// ---------------------------------------------------------------- weights cvt
__global__ __launch_bounds__(256) void cvt_w(
    const float* __restrict__ w0, const float* __restrict__ w1,
    const float* __restrict__ w2, const float* __restrict__ w3,
    ushort* __restrict__ dst) {
  const float* src = (blockIdx.y == 0) ? w0 : (blockIdx.y == 1) ? w1
                   : (blockIdx.y == 2) ? w2 : w3;
  ushort* d = dst + (size_t)blockIdx.y * 262144;
  int i = blockIdx.x * 256 + threadIdx.x;
  for (int j = i; j < 65536; j += 16384) {
    float4 v = ((const float4*)src)[j];
    ushort4 o = { f2bf(v.x), f2bf(v.y), f2bf(v.z), f2bf(v.w) };
    ((ushort4*)d)[j] = o;
  }
}

// ---------------------------------------------------------------- mask bits
__global__ __launch_bounds__(256) void mask_bits_kernel(
    const int* __restrict__ mask, unsigned long long* __restrict__ MB) {
  const int lane = threadIdx.x & 63;
  const int wv = (int)((blockIdx.x * 256 + threadIdx.x) >> 6);
  const size_t base = (size_t)wv * 64;
  for (int j = 0; j < 64; j += 4) {
    int v0 = mask[(base + j + 0) * 64 + lane];
    int v1 = mask[(base + j + 1) * 64 + lane];
    int v2 = mask[(base + j + 2) * 64 + lane];
    int v3 = mask[(base + j + 3) * 64 + lane];
    unsigned long long b0 = __ballot(v0 != 0), b1 = __ballot(v1 != 0);
    unsigned long long b2 = __ballot(v2 != 0), b3 = __ballot(v3 != 0);
    if (lane == 0) {
      MB[base + j] = b0; MB[base + j + 1] = b1;
      MB[base + j + 2] = b2; MB[base + j + 3] = b3;
    }
  }
}

// ---------------------------------------------------------------- QKV GEMM
// Y[8192][512] = X f32 [m][k] * W bf16 [n][k]; tile 128x128, BK=64, grid (64,4,3).
// z=0: Q, scale=0.125*log2(e); z=1: K; z=2: V transposed [b][h][hd][s].
__global__ __launch_bounds__(256, 3) void qkv_gemm(
    const float* __restrict__ q, const float* __restrict__ k,
    const float* __restrict__ v, const ushort* __restrict__ Wb,
    const float* __restrict__ bq, const float* __restrict__ bk,
    const float* __restrict__ bv, ushort* __restrict__ Qh,
    ushort* __restrict__ Kh, ushort* __restrict__ Vt) {
  __shared__ float  Asf[128 * 64];    // 32 KB fp32 A tile (reused as 128x128 ushort T)
  __shared__ ushort Ws[128 * 64];     // 16 KB bf16 W tile
  const int z = blockIdx.z;
  const float* X = (z == 0) ? q : (z == 1) ? k : v;
  const ushort* W = Wb + (size_t)z * 262144;
  const float* bias = (z == 0) ? bq : (z == 1) ? bk : bv;
  const float scale = (z == 0) ? 0.18033688011112042f : 1.0f;
  ushort* Y = (z == 0) ? Qh : (z == 1) ? Kh : Vt;

  const int tid = threadIdx.x, wv = tid >> 6, l = tid & 63;
  const int quad = l >> 4, ln = l & 15;
  const int m0 = blockIdx.x * 128, n0 = blockIdx.y * 128;
  const int wm = (wv & 1) * 64, wn = (wv >> 1) * 64;
  const int srA = l >> 4, sA = l & 15, cA = sA >> 1, hA = sA & 1;
  const int srW = l >> 3, scW = l & 7;
  f32x4 acc[4][4] = {};

  for (int kk = 0; kk < 512; kk += 64) {
#pragma unroll
    for (int i = 0; i < 8; ++i) {      // A: 128 fp32 rows, 32/wave, 4 rows/instr
      int rowa = wv * 32 + i * 4 + srA;
      gll16(X + (size_t)(m0 + rowa) * 512 + kk + ((cA ^ (rowa & 7)) * 8 + hA * 4),
            Asf + (wv * 32 + i * 4) * 64);
    }
#pragma unroll
    for (int i = 0; i < 4; ++i) {      // W: 128 bf16 rows, 32/wave, 8 rows/instr
      int roww = wv * 32 + i * 8 + srW;
      gll16(W + (size_t)(n0 + roww) * 512 + kk + ((scW ^ (roww & 7)) * 8),
            Ws + (wv * 32 + i * 8) * 64);
    }
    __syncthreads();
#pragma unroll
    for (int ks = 0; ks < 2; ++ks) {
      bf16x8 a[4], bw[4];
#pragma unroll
      for (int mt = 0; mt < 4; ++mt) {
        int row = wm + mt * 16 + ln;
        int p = (ks * 4 + quad) ^ (row & 7);
        const float* ap = &Asf[row * 64 + p * 8];
        f32x4 x0 = *(const f32x4*)ap;
        f32x4 x1 = *(const f32x4*)(ap + 4);
        bf16x8 t;
#pragma unroll
        for (int j = 0; j < 4; ++j) { t[j] = (__bf16)x0[j]; t[4 + j] = (__bf16)x1[j]; }
        a[mt] = t;
      }
#pragma unroll
      for (int nt = 0; nt < 4; ++nt) {
        int row = wn + nt * 16 + ln;
        bw[nt] = *(const bf16x8*)&Ws[row * 64 + (((ks * 4 + quad) ^ (row & 7)) * 8)];
      }
#pragma unroll
      for (int mt = 0; mt < 4; ++mt)
#pragma unroll
        for (int nt = 0; nt < 4; ++nt)
          acc[mt][nt] = MFMA16(a[mt], bw[nt], acc[mt][nt]);
    }
    __syncthreads();
  }
  float bval[4];
#pragma unroll
  for (int nt = 0; nt < 4; ++nt) bval[nt] = bias[n0 + wn + nt * 16 + ln];

  if (z == 2) {
    // transpose via LDS: T[128 n][128 m] ushort, 16 chunks/row, xor-swizzled low3
    ushort* uT = (ushort*)Asf;
#pragma unroll
    for (int nt = 0; nt < 4; ++nt) {
      int row = wn + nt * 16 + ln;
#pragma unroll
      for (int mt = 0; mt < 4; ++mt) {
        int mbase = wm + mt * 16 + quad * 4;
        ushort4 pk;
        pk.x = f2bf(acc[mt][nt][0] + bval[nt]);
        pk.y = f2bf(acc[mt][nt][1] + bval[nt]);
        pk.z = f2bf(acc[mt][nt][2] + bval[nt]);
        pk.w = f2bf(acc[mt][nt][3] + bval[nt]);
        int c = (mbase >> 3) ^ (row & 7);
        *(ushort4*)&uT[row * 128 + c * 8 + (quad & 1) * 4] = pk;
      }
    }
    __syncthreads();
#pragma unroll
    for (int j = 0; j < 8; ++j) {
      int i = tid + j * 256;             // 128 rows x 16 chunks
      int row = i >> 4, cs = i & 15;
      int g = cs ^ (row & 7);
      uint4 d = *(const uint4*)&uT[row * 128 + cs * 8];
      int n = n0 + row, m = m0 + g * 8;
      int bb = m >> 11, s = m & 2047, h = n >> 6, hd = n & 63;
      *(uint4*)(Y + ((size_t)((bb * 8 + h) * 64 + hd)) * 2048 + s) = d;
    }
  } else {
#pragma unroll
    for (int mt = 0; mt < 4; ++mt)
#pragma unroll
      for (int nt = 0; nt < 4; ++nt) {
        int n = n0 + wn + nt * 16 + ln;
#pragma unroll
        for (int r = 0; r < 4; ++r) {
          int m = m0 + wm + mt * 16 + quad * 4 + r;
          float val = (acc[mt][nt][r] + bval[nt]) * scale;
          int bb = m >> 11, s = m & 2047, h = n >> 6, hd = n & 63;
          Y[(((size_t)(bb * 8 + h) * 2048) + s) * 64 + hd] = f2bf(val);
        }
      }
  }
}

// ---------------------------------------------------------------- attention (R4-exact)
__global__ __launch_bounds__(256, 4) void attn(
    const ushort* __restrict__ Qh, const ushort* __restrict__ Kh,
    const ushort* __restrict__ Vt, const unsigned long long* __restrict__ MB,
    ushort* __restrict__ O) {
  __shared__ ushort SMEM[16384];          // Ks 16KB | Vs 16KB (reused at end)
  ushort* Ks = SMEM;                      // [kv 128][d 64], chunk-swizzled
  ushort* Vs = SMEM + 8192;               // [hd 64][kv 128], chunk-swizzled
  const int tid = threadIdx.x, wv = tid >> 6, lane = tid & 63;
  const int hs = lane >> 5, lq = lane & 31;
  const int qh = wv >> 1, kvh = wv & 1;
  const int bh = blockIdx.x, qb = blockIdx.y;
  const size_t hoff = (size_t)bh * 2048 * 64;
  const int q0 = qb * 64;
  const int qg = q0 + qh * 32 + lq;
  const int srK = lane >> 3, scK = lane & 7;
  const int srV = lane >> 4, scV = lane & 15;

  bf16x8 qf[4];                            // B-frag: k = 16*ki + 8*hs + j
#pragma unroll
  for (int ki = 0; ki < 4; ++ki)
    qf[ki] = *(const bf16x8*)(Qh + hoff + (size_t)qg * 64 + ki * 16 + hs * 8);

  f32x16 po0 = {}, po1 = {};               // O^T accum, col=q
  float l_own = 0.f;
  const unsigned long long* mrow = MB + ((size_t)(bh >> 3) * 2048 + qg) * 32;

  for (int it = 0; it < 16; ++it) {
    const int kv0 = it * 128;
#pragma unroll
    for (int i = 0; i < 4; ++i) {
      int row = wv * 32 + i * 8 + srK;
      gll16(Kh + hoff + (size_t)(kv0 + row) * 64 + ((scK ^ (row & 7)) * 8),
            Ks + (wv * 32 + i * 8) * 64);
      int rv = wv * 16 + i * 4 + srV;
      gll16(Vt + hoff + (size_t)rv * 2048 + kv0 + ((scV ^ (rv & 7)) * 8),
            Vs + (wv * 16 + i * 4) * 128);
    }
    unsigned long long mbw = mrow[it * 2 + kvh];
    __syncthreads();

#pragma unroll
    for (int ch = 0; ch < 2; ++ch) {
      const int kvb = kvh * 64 + ch * 32;
      f32x16 sc_ = {};
#pragma unroll
      for (int ki = 0; ki < 4; ++ki) {
        int row = kvb + lq;
        bf16x8 ak = *(const bf16x8*)&Ks[row * 64 + (((2 * ki + hs) ^ (row & 7)) * 8)];
        sc_ = MFMA32(ak, qf[ki], sc_);
      }
      uint pk[8];
      float psum = 0.f;
#pragma unroll
      for (int c = 0; c < 4; ++c) {
        unsigned nib = (unsigned)(mbw >> (ch * 32 + c * 8 + hs * 4)) & 0xFu;
        float p0 = (nib & 1u) ? exp2f(sc_[4 * c + 0]) : 0.f;
        float p1 = (nib & 2u) ? exp2f(sc_[4 * c + 1]) : 0.f;
        float p2 = (nib & 4u) ? exp2f(sc_[4 * c + 2]) : 0.f;
        float p3 = (nib & 8u) ? exp2f(sc_[4 * c + 3]) : 0.f;
        psum += (p0 + p1) + (p2 + p3);
        pk[2 * c + 0] = (uint)f2bf(p0) | ((uint)f2bf(p1) << 16);
        pk[2 * c + 1] = (uint)f2bf(p2) | ((uint)f2bf(p3) << 16);
      }
      l_own += psum;
      uint bx[4];
#pragma unroll
      for (int t2 = 0; t2 < 2; ++t2)
#pragma unroll
        for (int b2 = 0; b2 < 2; ++b2) {
          uint snd = hs ? pk[4 * t2 + b2] : pk[4 * t2 + 2 + b2];
          bx[t2 * 2 + b2] = (uint)__shfl_xor((int)snd, 32);
        }
#pragma unroll
      for (int t2 = 0; t2 < 2; ++t2) {
        union { uint u[4]; bf16x8 v; } bp;
        bp.u[0] = hs ? bx[2 * t2 + 0] : pk[4 * t2 + 0];
        bp.u[1] = hs ? bx[2 * t2 + 1] : pk[4 * t2 + 1];
        bp.u[2] = hs ? pk[4 * t2 + 2] : bx[2 * t2 + 0];
        bp.u[3] = hs ? pk[4 * t2 + 3] : bx[2 * t2 + 1];
#pragma unroll
        for (int m2 = 0; m2 < 2; ++m2) {
          int hd = m2 * 32 + lq;
          int gch = (kvb >> 3) + 2 * t2 + hs;
          bf16x8 av = *(const bf16x8*)&Vs[hd * 128 + ((gch ^ (hd & 7)) * 8)];
          if (m2 == 0) po0 = MFMA32(av, bp.v, po0);
          else         po1 = MFMA32(av, bp.v, po1);
        }
      }
    }
    __syncthreads();
  }

  l_own += __shfl_xor(l_own, 32);
  float* psh = (float*)Ks;                 // [64 q][64 hd] f32
  float* lsh = (float*)Vs;                 // [qh][64]
  ushort* Osh = Vs + 256;                  // [64 q][72]
  if (kvh == 1) {
#pragma unroll
    for (int i = 0; i < 16; ++i) psh[(qh * 32 + i) * 64 + lane] = po0[i];
#pragma unroll
    for (int i = 0; i < 16; ++i) psh[(qh * 32 + 16 + i) * 64 + lane] = po1[i];
    lsh[qh * 64 + lane] = l_own;
  }
  __syncthreads();
  if (kvh == 0) {
    float linv = 1.0f / (l_own + lsh[qh * 64 + lane]);
    int row = qh * 32 + lq;
#pragma unroll
    for (int m2 = 0; m2 < 2; ++m2) {
#pragma unroll
      for (int c = 0; c < 4; ++c)
#pragma unroll
        for (int b2 = 0; b2 < 2; ++b2) {
          int r = 4 * c + 2 * b2;
          float v0, v1;
          if (m2 == 0) {
            v0 = (po0[r] + psh[(qh * 32 + r) * 64 + lane]) * linv;
            v1 = (po0[r + 1] + psh[(qh * 32 + r + 1) * 64 + lane]) * linv;
          } else {
            v0 = (po1[r] + psh[(qh * 32 + 16 + r) * 64 + lane]) * linv;
            v1 = (po1[r + 1] + psh[(qh * 32 + 16 + r + 1) * 64 + lane]) * linv;
          }
          int hd = m2 * 32 + 8 * c + 4 * hs + 2 * b2;
          *(uint*)&Osh[row * 72 + hd] = (uint)f2bf(v0) | ((uint)f2bf(v1) << 16);
        }
    }
  }
  __syncthreads();
  for (int i = tid; i < 512; i += 256) {
    int row = i >> 3, cc = i & 7;
    uint4 d = *(const uint4*)&Osh[row * 72 + cc * 8];
    *(uint4*)(O + ((size_t)((bh >> 3) * 2048 + q0 + row)) * 512 +
              (bh & 7) * 64 + cc * 8) = d;
  }
}

// ---------------------------------------------------------------- out proj
__global__ __launch_bounds__(256) void out_gemm(
    const ushort* __restrict__ X, const ushort* __restrict__ W,
    const float* __restrict__ bias, float* __restrict__ Y) {
  __shared__ ushort As[64 * 64];
  __shared__ ushort Ws[128 * 64];
  const int tid = threadIdx.x, wv = tid >> 6, l = tid & 63;
  const int quad = l >> 4, ln = l & 15;
  const int m0 = blockIdx.x * 64, n0 = blockIdx.y * 128;
  const int wm = (wv & 1) * 32, wn = (wv >> 1) * 64;
  const int sr = l >> 3, sc = l & 7;
  f32x4 acc[2][4] = {};
  for (int kk = 0; kk < 512; kk += 64) {
#pragma unroll
    for (int i = 0; i < 2; ++i) {
      int row = wv * 16 + i * 8 + sr;
      gll16(X + (size_t)(m0 + row) * 512 + kk + ((sc ^ (row & 7)) * 8),
            As + (wv * 16 + i * 8) * 64);
    }
#pragma unroll
    for (int i = 0; i < 4; ++i) {
      int row = wv * 32 + i * 8 + sr;
      gll16(W + (size_t)(n0 + row) * 512 + kk + ((sc ^ (row & 7)) * 8),
            Ws + (wv * 32 + i * 8) * 64);
    }
    __syncthreads();
#pragma unroll
    for (int ks = 0; ks < 2; ++ks) {
      bf16x8 a[2], bw[4];
#pragma unroll
      for (int mt = 0; mt < 2; ++mt) {
        int row = wm + mt * 16 + ln;
        a[mt] = *(const bf16x8*)&As[row * 64 + (((ks * 4 + quad) ^ (row & 7)) * 8)];
      }
#pragma unroll
      for (int nt = 0; nt < 4; ++nt) {
        int row = wn + nt * 16 + ln;
        bw[nt] = *(const bf16x8*)&Ws[row * 64 + (((ks * 4 + quad) ^ (row & 7)) * 8)];
      }
#pragma unroll
      for (int mt = 0; mt < 2; ++mt)
#pragma unroll
        for (int nt = 0; nt < 4; ++nt)
          acc[mt][nt] = MFMA16(a[mt], bw[nt], acc[mt][nt]);
    }
    __syncthreads();
  }
#pragma unroll
  for (int mt = 0; mt < 2; ++mt)
#pragma unroll
    for (int nt = 0; nt < 4; ++nt) {
      int n = n0 + wn + nt * 16 + ln;
      float bval = bias[n];
#pragma unroll
      for (int r = 0; r < 4; ++r) {
        int m = m0 + wm + mt * 16 + quad * 4 + r;
        Y[(size_t)m * 512 + n] = acc[mt][nt][r] + bval;
      }
    }
}

// ---------------------------------------------------------------- launch
extern "C" void kernel_launch(void* const* d_in, const int* in_sizes, int n_in,
                              void* d_out, int out_size, void* d_ws, size_t ws_size,
                              hipStream_t stream) {
  const float* q    = (const float*)d_in[0];
  const float* k    = (const float*)d_in[1];
  const float* v    = (const float*)d_in[2];
  const int*   mask = (const int*)d_in[3];
  const float* Wq   = (const float*)d_in[4];
  const float* bq   = (const float*)d_in[5];
  const float* Wk   = (const float*)d_in[6];
  const float* bk   = (const float*)d_in[7];
  const float* Wv   = (const float*)d_in[8];
  const float* bv   = (const float*)d_in[9];
  const float* Wo   = (const float*)d_in[10];
  const float* bo   = (const float*)d_in[11];
  float* out = (float*)d_out;

  uint8_t* ws = (uint8_t*)d_ws;
  const size_t MiB = 1u << 20;
  ushort* Oh = (ushort*)(ws + 0 * MiB);
  ushort* Qh = (ushort*)(ws + 8 * MiB);
  ushort* Kh = (ushort*)(ws + 16 * MiB);
  ushort* Vt = (ushort*)(ws + 24 * MiB);
  unsigned long long* MB = (unsigned long long*)(ws + 32 * MiB);
  ushort* Wb = (ushort*)(ws + 34 * MiB);

  cvt_w<<<dim3(64, 4), 256, 0, stream>>>(Wq, Wk, Wv, Wo, Wb);
  mask_bits_kernel<<<1024, 256, 0, stream>>>(mask, MB);
  qkv_gemm<<<dim3(64, 4, 3), 256, 0, stream>>>(q, k, v, Wb, bq, bk, bv, Qh, Kh, Vt);
  attn<<<dim3(32, 32), 256, 0, stream>>>(Qh, Kh, Vt, MB, Oh);
  out_gemm<<<dim3(128, 4), 256, 0, stream>>>(Oh, Wb + 3 * 262144, bo, out);
}

// Round 7
// 261.850 us; speedup vs baseline: 2.0698x; 1.0253x over previous
//
#include <hip/hip_runtime.h>
#include <cstdint>

// B=4, S=2048, H=512, NH=8, HD=64 — 5 launches:
//   cvt_w | mask_bits | qkv_gemm (128x128, fp32-staged, perm-cvt, z=q/k/v) |
//   attn (raw v_exp, v_perm pack, ones-MFMA rowsum) | out_gemm
// ws: Oh 0-8Mi | Qh 8-16 | Kh 16-24 | Vt 24-32 | MB 32-34 | Wb 34-36 MiB

typedef __bf16 bf16x8 __attribute__((ext_vector_type(8)));
typedef float  f32x4  __attribute__((ext_vector_type(4)));
typedef float  f32x16 __attribute__((ext_vector_type(16)));

#define MFMA16(a, b, c) __builtin_amdgcn_mfma_f32_16x16x32_bf16(a, b, c, 0, 0, 0)
#define MFMA32(a, b, c) __builtin_amdgcn_mfma_f32_32x32x16_bf16(a, b, c, 0, 0, 0)

// round-half-up f32->bf16 (cheap: add + shift); ties differ from RTNE by <=1/2 ulp
__device__ __forceinline__ ushort f2bf(float f) {
  union { float f; uint32_t u; } v; v.f = f;
  return (ushort)((v.u + 0x8000u) >> 16);
}
// pack two f32 -> bf16x2 in one v_perm_b32
__device__ __forceinline__ uint packbf(float a, float b) {
  union { float f; uint32_t u; } x, y; x.f = a; y.f = b;
#if __has_builtin(__builtin_amdgcn_perm)
  return __builtin_amdgcn_perm(y.u + 0x8000u, x.u + 0x8000u, 0x07060302u);
#else
  return ((x.u + 0x8000u) >> 16) | ((y.u + 0x8000u) & 0xffff0000u);
#endif
}
__device__ __forceinline__ float exp2r(float x) {
#if __has_builtin(__builtin_amdgcn_exp2f)
  return __builtin_amdgcn_exp2f(x);
#else
  return exp2f(x);
#endif
}

typedef const __attribute__((address_space(1))) unsigned int* gas_u32;
typedef __attribute__((address_space(3))) unsigned int* las_u32;
__device__ __forceinline__ void gll16(const void* g, void* l) {
  __builtin_amdgcn_global_load_lds((gas_u32)g, (las_u32)l, 16, 0, 0);
}

// ---------------------------------------------------------------- weights cvt
__global__ __launch_bounds__(256) void cvt_w(
    const float* __restrict__ w0, const float* __restrict__ w1,
    const float* __restrict__ w2, const float* __restrict__ w3,
    ushort* __restrict__ dst) {
  const float* src = (blockIdx.y == 0) ? w0 : (blockIdx.y == 1) ? w1
                   : (blockIdx.y == 2) ? w2 : w3;
  ushort* d = dst + (size_t)blockIdx.y * 262144;
  int i = blockIdx.x * 256 + threadIdx.x;
  for (int j = i; j < 65536; j += 16384) {
    float4 v = ((const float4*)src)[j];
    uint2 o = { packbf(v.x, v.y), packbf(v.z, v.w) };
    ((uint2*)d)[j] = o;
  }
}

// ---------------------------------------------------------------- mask bits
__global__ __launch_bounds__(256) void mask_bits_kernel(
    const int* __restrict__ mask, unsigned long long* __restrict__ MB) {
  const int lane = threadIdx.x & 63;
  const int wv = (int)((blockIdx.x * 256 + threadIdx.x) >> 6);
  const size_t base = (size_t)wv * 64;
  for (int j = 0; j < 64; j += 4) {
    int v0 = mask[(base + j + 0) * 64 + lane];
    int v1 = mask[(base + j + 1) * 64 + lane];
    int v2 = mask[(base + j + 2) * 64 + lane];
    int v3 = mask[(base + j + 3) * 64 + lane];
    unsigned long long b0 = __ballot(v0 != 0), b1 = __ballot(v1 != 0);
    unsigned long long b2 = __ballot(v2 != 0), b3 = __ballot(v3 != 0);
    if (lane == 0) {
      MB[base + j] = b0; MB[base + j + 1] = b1;
      MB[base + j + 2] = b2; MB[base + j + 3] = b3;
    }
  }
}

// ---------------------------------------------------------------- QKV GEMM
// Y[8192][512] = X f32 [m][k] * W bf16 [n][k]; tile 128x128, BK=64, grid (64,4,3).
// z=0: Q, scale=0.125*log2(e); z=1: K; z=2: V transposed [b][h][hd][s].
__global__ __launch_bounds__(256, 3) void qkv_gemm(
    const float* __restrict__ q, const float* __restrict__ k,
    const float* __restrict__ v, const ushort* __restrict__ Wb,
    const float* __restrict__ bq, const float* __restrict__ bk,
    const float* __restrict__ bv, ushort* __restrict__ Qh,
    ushort* __restrict__ Kh, ushort* __restrict__ Vt) {
  __shared__ ushort SH[128 * 136];    // 34 KB: fp32 A tile [128][64] / epi buffers
  __shared__ ushort Ws[128 * 64];     // 16 KB bf16 W tile
  float* Asf = (float*)SH;
  const int z = blockIdx.z;
  const float* X = (z == 0) ? q : (z == 1) ? k : v;
  const ushort* W = Wb + (size_t)z * 262144;
  const float* bias = (z == 0) ? bq : (z == 1) ? bk : bv;
  const float scale = (z == 0) ? 0.18033688011112042f : 1.0f;
  ushort* Y = (z == 0) ? Qh : (z == 1) ? Kh : Vt;

  const int tid = threadIdx.x, wv = tid >> 6, l = tid & 63;
  const int quad = l >> 4, ln = l & 15;
  const int m0 = blockIdx.x * 128, n0 = blockIdx.y * 128;
  const int wm = (wv & 1) * 64, wn = (wv >> 1) * 64;
  const int srA = l >> 4, sA = l & 15, cA = sA >> 1, hA = sA & 1;
  const int srW = l >> 3, scW = l & 7;
  f32x4 acc[4][4] = {};

  for (int kk = 0; kk < 512; kk += 64) {
#pragma unroll
    for (int i = 0; i < 8; ++i) {      // A: 128 fp32 rows, 32/wave, 4 rows/instr
      int rowa = wv * 32 + i * 4 + srA;
      gll16(X + (size_t)(m0 + rowa) * 512 + kk + ((cA ^ (rowa & 7)) * 8 + hA * 4),
            Asf + (wv * 32 + i * 4) * 64);
    }
#pragma unroll
    for (int i = 0; i < 4; ++i) {      // W: 128 bf16 rows, 32/wave, 8 rows/instr
      int roww = wv * 32 + i * 8 + srW;
      gll16(W + (size_t)(n0 + roww) * 512 + kk + ((scW ^ (roww & 7)) * 8),
            Ws + (wv * 32 + i * 8) * 64);
    }
    __syncthreads();
#pragma unroll
    for (int ks = 0; ks < 2; ++ks) {
      bf16x8 a[4], bw[4];
#pragma unroll
      for (int mt = 0; mt < 4; ++mt) {
        int row = wm + mt * 16 + ln;
        int p = (ks * 4 + quad) ^ (row & 7);
        const float* ap = &Asf[row * 64 + p * 8];
        f32x4 x0 = *(const f32x4*)ap;
        f32x4 x1 = *(const f32x4*)(ap + 4);
        union { uint u[4]; bf16x8 v; } t;
        t.u[0] = packbf(x0[0], x0[1]);
        t.u[1] = packbf(x0[2], x0[3]);
        t.u[2] = packbf(x1[0], x1[1]);
        t.u[3] = packbf(x1[2], x1[3]);
        a[mt] = t.v;
      }
#pragma unroll
      for (int nt = 0; nt < 4; ++nt) {
        int row = wn + nt * 16 + ln;
        bw[nt] = *(const bf16x8*)&Ws[row * 64 + (((ks * 4 + quad) ^ (row & 7)) * 8)];
      }
#pragma unroll
      for (int mt = 0; mt < 4; ++mt)
#pragma unroll
        for (int nt = 0; nt < 4; ++nt)
          acc[mt][nt] = MFMA16(a[mt], bw[nt], acc[mt][nt]);
    }
    __syncthreads();
  }
  float bval[4];
#pragma unroll
  for (int nt = 0; nt < 4; ++nt) bval[nt] = bias[n0 + wn + nt * 16 + ln];

  if (z == 2) {
    // transpose via LDS: T[128 n][128 m] ushort, xor-swizzled chunks
    ushort* uT = SH;
#pragma unroll
    for (int nt = 0; nt < 4; ++nt) {
      int row = wn + nt * 16 + ln;
#pragma unroll
      for (int mt = 0; mt < 4; ++mt) {
        int mbase = wm + mt * 16 + quad * 4;
        uint2 pk = { packbf(acc[mt][nt][0] + bval[nt], acc[mt][nt][1] + bval[nt]),
                     packbf(acc[mt][nt][2] + bval[nt], acc[mt][nt][3] + bval[nt]) };
        int c = (mbase >> 3) ^ (row & 7);
        *(uint2*)&uT[row * 128 + c * 8 + (quad & 1) * 4] = pk;
      }
    }
    __syncthreads();
#pragma unroll
    for (int j = 0; j < 8; ++j) {
      int i = tid + j * 256;             // 128 rows x 16 chunks
      int row = i >> 4, cs = i & 15;
      int g = cs ^ (row & 7);
      uint4 d = *(const uint4*)&uT[row * 128 + cs * 8];
      int n = n0 + row, m = m0 + g * 8;
      int bb = m >> 11, s = m & 2047, h = n >> 6, hd = n & 63;
      *(uint4*)(Y + ((size_t)((bb * 8 + h) * 64 + hd)) * 2048 + s) = d;
    }
  } else {
    // EPI0: LDS [m 128][n 136] round-trip -> vectorized head-split stores
    ushort* uM = SH;
#pragma unroll
    for (int mt = 0; mt < 4; ++mt)
#pragma unroll
      for (int nt = 0; nt < 4; ++nt) {
        int n = wn + nt * 16 + ln;
#pragma unroll
        for (int r = 0; r < 4; ++r) {
          int m = wm + mt * 16 + quad * 4 + r;
          uM[m * 136 + n] = f2bf((acc[mt][nt][r] + bval[nt]) * scale);
        }
      }
    __syncthreads();
#pragma unroll
    for (int j = 0; j < 8; ++j) {
      int i = tid + j * 256;             // 128 rows x 16 chunks of 8
      int row = i >> 4, cs = i & 15;
      uint4 d = *(const uint4*)&uM[row * 136 + cs * 8];
      int m = m0 + row, n = n0 + cs * 8;
      int bb = m >> 11, s = m & 2047, h = n >> 6, hd = n & 63;
      *(uint4*)(Y + (((size_t)(bb * 8 + h) * 2048) + s) * 64 + hd) = d;
    }
  }
}

// ---------------------------------------------------------------- attention
// 32x32x16 MFMA, S^T = K.Q^T, P^T->B-frag via shfl_xor(32); l via ones-MFMA.
__global__ __launch_bounds__(256, 4) void attn(
    const ushort* __restrict__ Qh, const ushort* __restrict__ Kh,
    const ushort* __restrict__ Vt, const unsigned long long* __restrict__ MB,
    ushort* __restrict__ O) {
  __shared__ ushort SMEM[16384];          // Ks 16KB | Vs 16KB (reused at end)
  ushort* Ks = SMEM;                      // [kv 128][d 64], chunk-swizzled
  ushort* Vs = SMEM + 8192;               // [hd 64][kv 128], chunk-swizzled
  const int tid = threadIdx.x, wv = tid >> 6, lane = tid & 63;
  const int hs = lane >> 5, lq = lane & 31;
  const int qh = wv >> 1, kvh = wv & 1;
  const int bh = blockIdx.x, qb = blockIdx.y;
  const size_t hoff = (size_t)bh * 2048 * 64;
  const int q0 = qb * 64;
  const int qg = q0 + qh * 32 + lq;
  const int srK = lane >> 3, scK = lane & 7;
  const int srV = lane >> 4, scV = lane & 15;

  bf16x8 qf[4];                            // B-frag: k = 16*ki + 8*hs + j
#pragma unroll
  for (int ki = 0; ki < 4; ++ki)
    qf[ki] = *(const bf16x8*)(Qh + hoff + (size_t)qg * 64 + ki * 16 + hs * 8);

  bf16x8 ones;
#pragma unroll
  for (int j = 0; j < 8; ++j) ones[j] = (__bf16)1.0f;

  f32x16 po0 = {}, po1 = {};               // O^T accum, col=q
  f32x16 lacc = {};                        // row-sum accum (all regs equal)
  const unsigned long long* mrow = MB + ((size_t)(bh >> 3) * 2048 + qg) * 32;

  for (int it = 0; it < 16; ++it) {
    const int kv0 = it * 128;
#pragma unroll
    for (int i = 0; i < 4; ++i) {
      int row = wv * 32 + i * 8 + srK;
      gll16(Kh + hoff + (size_t)(kv0 + row) * 64 + ((scK ^ (row & 7)) * 8),
            Ks + (wv * 32 + i * 8) * 64);
      int rv = wv * 16 + i * 4 + srV;
      gll16(Vt + hoff + (size_t)rv * 2048 + kv0 + ((scV ^ (rv & 7)) * 8),
            Vs + (wv * 16 + i * 4) * 128);
    }
    unsigned long long mbw = mrow[it * 2 + kvh];
    __syncthreads();

#pragma unroll
    for (int ch = 0; ch < 2; ++ch) {
      const int kvb = kvh * 64 + ch * 32;
      f32x16 sc_ = {};
#pragma unroll
      for (int ki = 0; ki < 4; ++ki) {
        int row = kvb + lq;
        bf16x8 ak = *(const bf16x8*)&Ks[row * 64 + (((2 * ki + hs) ^ (row & 7)) * 8)];
        sc_ = MFMA32(ak, qf[ki], sc_);
      }
      uint pk[8];
#pragma unroll
      for (int c = 0; c < 4; ++c) {
        unsigned nib = (unsigned)(mbw >> (ch * 32 + c * 8 + hs * 4)) & 0xFu;
        float p0 = (nib & 1u) ? exp2r(sc_[4 * c + 0]) : 0.f;
        float p1 = (nib & 2u) ? exp2r(sc_[4 * c + 1]) : 0.f;
        float p2 = (nib & 4u) ? exp2r(sc_[4 * c + 2]) : 0.f;
        float p3 = (nib & 8u) ? exp2r(sc_[4 * c + 3]) : 0.f;
        pk[2 * c + 0] = packbf(p0, p1);
        pk[2 * c + 1] = packbf(p2, p3);
      }
      uint bx[4];
#pragma unroll
      for (int t2 = 0; t2 < 2; ++t2)
#pragma unroll
        for (int b2 = 0; b2 < 2; ++b2) {
          uint snd = hs ? pk[4 * t2 + b2] : pk[4 * t2 + 2 + b2];
          bx[t2 * 2 + b2] = (uint)__shfl_xor((int)snd, 32);
        }
#pragma unroll
      for (int t2 = 0; t2 < 2; ++t2) {
        union { uint u[4]; bf16x8 v; } bp;
        bp.u[0] = hs ? bx[2 * t2 + 0] : pk[4 * t2 + 0];
        bp.u[1] = hs ? bx[2 * t2 + 1] : pk[4 * t2 + 1];
        bp.u[2] = hs ? pk[4 * t2 + 2] : bx[2 * t2 + 0];
        bp.u[3] = hs ? pk[4 * t2 + 3] : bx[2 * t2 + 1];
        lacc = MFMA32(ones, bp.v, lacc);   // row-sum of P, col=q
#pragma unroll
        for (int m2 = 0; m2 < 2; ++m2) {
          int hd = m2 * 32 + lq;
          int gch = (kvb >> 3) + 2 * t2 + hs;
          bf16x8 av = *(const bf16x8*)&Vs[hd * 128 + ((gch ^ (hd & 7)) * 8)];
          if (m2 == 0) po0 = MFMA32(av, bp.v, po0);
          else         po1 = MFMA32(av, bp.v, po1);
        }
      }
    }
    __syncthreads();
  }

  float l_own = lacc[0];                   // full sum over this wave's kv half
  float* psh = (float*)Ks;                 // [64 q][64 hd] f32
  float* lsh = (float*)Vs;                 // [qh][64]
  ushort* Osh = Vs + 256;                  // [64 q][72]
  if (kvh == 1) {
#pragma unroll
    for (int i = 0; i < 16; ++i) psh[(qh * 32 + i) * 64 + lane] = po0[i];
#pragma unroll
    for (int i = 0; i < 16; ++i) psh[(qh * 32 + 16 + i) * 64 + lane] = po1[i];
    lsh[qh * 64 + lane] = l_own;
  }
  __syncthreads();
  if (kvh == 0) {
    float linv = 1.0f / (l_own + lsh[qh * 64 + lane]);
    int row = qh * 32 + lq;
#pragma unroll
    for (int m2 = 0; m2 < 2; ++m2) {
#pragma unroll
      for (int c = 0; c < 4; ++c)
#pragma unroll
        for (int b2 = 0; b2 < 2; ++b2) {
          int r = 4 * c + 2 * b2;
          float v0, v1;
          if (m2 == 0) {
            v0 = (po0[r] + psh[(qh * 32 + r) * 64 + lane]) * linv;
            v1 = (po0[r + 1] + psh[(qh * 32 + r + 1) * 64 + lane]) * linv;
          } else {
            v0 = (po1[r] + psh[(qh * 32 + 16 + r) * 64 + lane]) * linv;
            v1 = (po1[r + 1] + psh[(qh * 32 + 16 + r + 1) * 64 + lane]) * linv;
          }
          int hd = m2 * 32 + 8 * c + 4 * hs + 2 * b2;
          *(uint*)&Osh[row * 72 + hd] = packbf(v0, v1);
        }
    }
  }
  __syncthreads();
  for (int i = tid; i < 512; i += 256) {
    int row = i >> 3, cc = i & 7;
    uint4 d = *(const uint4*)&Osh[row * 72 + cc * 8];
    *(uint4*)(O + ((size_t)((bh >> 3) * 2048 + q0 + row)) * 512 +
              (bh & 7) * 64 + cc * 8) = d;
  }
}

// ---------------------------------------------------------------- out proj
__global__ __launch_bounds__(256) void out_gemm(
    const ushort* __restrict__ X, const ushort* __restrict__ W,
    const float* __restrict__ bias, float* __restrict__ Y) {
  __shared__ ushort As[64 * 64];
  __shared__ ushort Ws[128 * 64];
  const int tid = threadIdx.x, wv = tid >> 6, l = tid & 63;
  const int quad = l >> 4, ln = l & 15;
  const int m0 = blockIdx.x * 64, n0 = blockIdx.y * 128;
  const int wm = (wv & 1) * 32, wn = (wv >> 1) * 64;
  const int sr = l >> 3, sc = l & 7;
  f32x4 acc[2][4] = {};
  for (int kk = 0; kk < 512; kk += 64) {
#pragma unroll
    for (int i = 0; i < 2; ++i) {
      int row = wv * 16 + i * 8 + sr;
      gll16(X + (size_t)(m0 + row) * 512 + kk + ((sc ^ (row & 7)) * 8),
            As + (wv * 16 + i * 8) * 64);
    }
#pragma unroll
    for (int i = 0; i < 4; ++i) {
      int row = wv * 32 + i * 8 + sr;
      gll16(W + (size_t)(n0 + row) * 512 + kk + ((sc ^ (row & 7)) * 8),
            Ws + (wv * 32 + i * 8) * 64);
    }
    __syncthreads();
#pragma unroll
    for (int ks = 0; ks < 2; ++ks) {
      bf16x8 a[2], bw[4];
#pragma unroll
      for (int mt = 0; mt < 2; ++mt) {
        int row = wm + mt * 16 + ln;
        a[mt] = *(const bf16x8*)&As[row * 64 + (((ks * 4 + quad) ^ (row & 7)) * 8)];
      }
#pragma unroll
      for (int nt = 0; nt < 4; ++nt) {
        int row = wn + nt * 16 + ln;
        bw[nt] = *(const bf16x8*)&Ws[row * 64 + (((ks * 4 + quad) ^ (row & 7)) * 8)];
      }
#pragma unroll
      for (int mt = 0; mt < 2; ++mt)
#pragma unroll
        for (int nt = 0; nt < 4; ++nt)
          acc[mt][nt] = MFMA16(a[mt], bw[nt], acc[mt][nt]);
    }
    __syncthreads();
  }
#pragma unroll
  for (int mt = 0; mt < 2; ++mt)
#pragma unroll
    for (int nt = 0; nt < 4; ++nt) {
      int n = n0 + wn + nt * 16 + ln;
      float bval = bias[n];
#pragma unroll
      for (int r = 0; r < 4; ++r) {
        int m = m0 + wm + mt * 16 + quad * 4 + r;
        Y[(size_t)m * 512 + n] = acc[mt][nt][r] + bval;
      }
    }
}

// ---------------------------------------------------------------- launch
extern "C" void kernel_launch(void* const* d_in, const int* in_sizes, int n_in,
                              void* d_out, int out_size, void* d_ws, size_t ws_size,
                              hipStream_t stream) {
  const float* q    = (const float*)d_in[0];
  const float* k    = (const float*)d_in[1];
  const float* v    = (const float*)d_in[2];
  const int*   mask = (const int*)d_in[3];
  const float* Wq   = (const float*)d_in[4];
  const float* bq   = (const float*)d_in[5];
  const float* Wk   = (const float*)d_in[6];
  const float* bk   = (const float*)d_in[7];
  const float* Wv   = (const float*)d_in[8];
  const float* bv   = (const float*)d_in[9];
  const float* Wo   = (const float*)d_in[10];
  const float* bo   = (const float*)d_in[11];
  float* out = (float*)d_out;

  uint8_t* ws = (uint8_t*)d_ws;
  const size_t MiB = 1u << 20;
  ushort* Oh = (ushort*)(ws + 0 * MiB);
  ushort* Qh = (ushort*)(ws + 8 * MiB);
  ushort* Kh = (ushort*)(ws + 16 * MiB);
  ushort* Vt = (ushort*)(ws + 24 * MiB);
  unsigned long long* MB = (unsigned long long*)(ws + 32 * MiB);
  ushort* Wb = (ushort*)(ws + 34 * MiB);

  cvt_w<<<dim3(64, 4), 256, 0, stream>>>(Wq, Wk, Wv, Wo, Wb);
  mask_bits_kernel<<<1024, 256, 0, stream>>>(mask, MB);
  qkv_gemm<<<dim3(64, 4, 3), 256, 0, stream>>>(q, k, v, Wb, bq, bk, bv, Qh, Kh, Vt);
  attn<<<dim3(32, 32), 256, 0, stream>>>(Qh, Kh, Vt, MB, Oh);
  out_gemm<<<dim3(128, 4), 256, 0, stream>>>(Oh, Wb + 3 * 262144, bo, out);
}